// Round 6
// baseline (471.309 us; speedup 1.0000x reference)
//
#include <hip/hip_runtime.h>
#include <math.h>

// ---------------- sizes ----------------
#define DD 256
#define KK 512
#define LL 64
#define BB 8
#define SS 16
#define F_LOG2PI 1.83787706641f
#define PER_I 16777216u   // i-stride in per-half eps flat index (64*16*64*256)

// ---------------- threefry2x32 (JAX-compatible) ----------------
struct U2 { unsigned x, y; };

__host__ __device__ constexpr U2 tf2x32(unsigned k0, unsigned k1, unsigned c0, unsigned c1) {
  unsigned ks2 = k0 ^ k1 ^ 0x1BD11BDAu;
  unsigned x0 = c0 + k0;
  unsigned x1 = c1 + k1;
#define TFR(r) { x0 += x1; x1 = (x1 << (r)) | (x1 >> (32 - (r))); x1 ^= x0; }
  TFR(13) TFR(15) TFR(26) TFR(6)   x0 += k1;  x1 += ks2 + 1u;
  TFR(17) TFR(29) TFR(16) TFR(24)  x0 += ks2; x1 += k0 + 2u;
  TFR(13) TFR(15) TFR(26) TFR(6)   x0 += k0;  x1 += k1 + 3u;
  TFR(17) TFR(29) TFR(16) TFR(24)  x0 += k1;  x1 += ks2 + 4u;
  TFR(13) TFR(15) TFR(26) TFR(6)   x0 += ks2; x1 += k0 + 5u;
#undef TFR
  return U2{x0, x1};
}

// Guaranteed single-instruction rotate-left: v_alignbit_b32 computes
// ({S0,S1} >> S2) & 0xffffffff, so alignbit(x,x,32-r) == rotl(x,r).
__device__ inline unsigned rotl(unsigned x, unsigned r) {
  return __builtin_amdgcn_alignbit(x, x, 32u - r);
}

// Threefry with c0=0 and k1 pre-folded into the counter (x1 = c1 + k1).
// Returns x0 ^ x1 (the JAX partitionable 32-bit draw). Explicit alignbit.
__device__ inline unsigned tf_fold(unsigned k0, unsigned k1, unsigned x1) {
  unsigned ks2 = k0 ^ k1 ^ 0x1BD11BDAu;
  unsigned x0 = k0;
#define TFR(r) { x0 += x1; x1 = rotl(x1, r); x1 ^= x0; }
  TFR(13u) TFR(15u) TFR(26u) TFR(6u)   x0 += k1;  x1 += ks2 + 1u;
  TFR(17u) TFR(29u) TFR(16u) TFR(24u)  x0 += ks2; x1 += k0 + 2u;
  TFR(13u) TFR(15u) TFR(26u) TFR(6u)   x0 += k0;  x1 += k1 + 3u;
  TFR(17u) TFR(29u) TFR(16u) TFR(24u)  x0 += k1;  x1 += ks2 + 4u;
  TFR(13u) TFR(15u) TFR(26u) TFR(6u)   x0 += ks2; x1 += k0 + 5u;
#undef TFR
  return x0 ^ x1;
}

// bits -> p*u where eps = sqrt2 * p * u (sqrt2 folded into caller's scale).
// u = (bitcast((b>>9)|0x40000000) - 3.0f) == exact(2f-1) via Sterbenz; differs
// from ref's fmaf(f,2,-0.99999994) by exactly 2^-24 (negligible, samples same).
// Clamp kept: b>>9==0 (~16 times in 134M) must not hit log(0).
__device__ inline float normal_pu(unsigned b) {
  float two_fp = __uint_as_float((b >> 9) | 0x40000000u);     // 2*(1+frac) in [2,4)
  float u = fmaxf(-0.99999994f, two_fp - 3.0f);
  float w = -__logf(fmaf(-u, u, 1.0f));                       // -log(1-u*u)
  float p;
  if (__ballot(w >= 5.0f) == 0ull) {                          // wave-uniform
    float ww = w - 2.5f;
    p =            2.81022636e-08f;
    p = fmaf(p, ww, 3.43273939e-07f);
    p = fmaf(p, ww, -3.5233877e-06f);
    p = fmaf(p, ww, -4.39150654e-06f);
    p = fmaf(p, ww,  0.00021858087f);
    p = fmaf(p, ww, -0.00125372503f);
    p = fmaf(p, ww, -0.00417768164f);
    p = fmaf(p, ww,  0.246640727f);
    p = fmaf(p, ww,  1.50140941f);
  } else {
    bool s = w < 5.0f;
    float ww = s ? (w - 2.5f) : (__builtin_amdgcn_sqrtf(w) - 3.0f);
    p =          s ?  2.81022636e-08f : -0.000200214257f;
    p = fmaf(p, ww, s ?  3.43273939e-07f :  0.000100950558f);
    p = fmaf(p, ww, s ? -3.5233877e-06f  :  0.00134934322f);
    p = fmaf(p, ww, s ? -4.39150654e-06f : -0.00367342844f);
    p = fmaf(p, ww, s ?  0.00021858087f  :  0.00573950773f);
    p = fmaf(p, ww, s ? -0.00125372503f  : -0.0076224613f);
    p = fmaf(p, ww, s ? -0.00417768164f  :  0.00943887047f);
    p = fmaf(p, ww, s ?  0.246640727f    :  1.00167406f);
    p = fmaf(p, ww, s ?  1.50140941f     :  2.83297682f);
  }
  return p * u;
}

// ---------------- kernels ----------------

// Stable counting-sort of balanced labels (robust to int64 labels).
__global__ void k_sort(const int* __restrict__ labels, int* __restrict__ pos,
                       int* __restrict__ lmap) {
  __shared__ int lab[512];
  __shared__ int cnt[64];
  __shared__ int mode;
  int t = threadIdx.x;
  int v = labels[t];
  if (t < 64) cnt[t] = 0;
  if (t == 0) mode = 0;
  __syncthreads();
  atomicAdd(&cnt[v & 63], 1);
  __syncthreads();
  if (t < 64 && cnt[t] != 8) mode = 1;
  __syncthreads();
  if (mode) v = labels[2 * t];           // int64 little-endian low words
  lab[t] = v & 63;
  __syncthreads();
  int c = lab[t];
  int o = 0;
  for (int j = 0; j < t; ++j) o += (lab[j] == c);
  pos[c * 8 + o] = t;
  if (t < 64) lmap[t] = t;
}

// Prototype fusion per (half, class l).
__global__ void k_protos(const float* __restrict__ P, const float* __restrict__ he_p,
                         const int* __restrict__ pos, float* __restrict__ pm,
                         float* __restrict__ pe, float4* __restrict__ pq,
                         float* __restrict__ cl) {
  int hb = blockIdx.x;             // h*64 + l
  int h = hb >> 6, l = hb & 63;
  int d = threadIdx.x;
  float eps_var = expf(he_p[0]);
  int soff = h ? 0 : 4;            // support rows for this half
  float sinv = 0.f, sminv = 0.f;
#pragma unroll
  for (int j = 0; j < 4; ++j) {
    int row = pos[l * 8 + soff + j];
    float m = P[row * KK + d];
    float hh = P[row * KK + DD + d];
    float vv = eps_var + expf(hh);
    float iv = 1.0f / vv;
    sinv += iv; sminv += m * iv;
  }
  float nv = 1.0f / sinv;
  float nm = nv * sminv;
  float ev = eps_var + nv;         // exp(h_proto)
  pm[hb * DD + d] = nm;
  pe[hb * DD + d] = ev;
  float4 rec; rec.x = nm; rec.y = ev; rec.z = 1.0f / ev; rec.w = 0.0f;
  pq[(h * 256 + d) * 64 + l] = rec;
  float t = F_LOG2PI + __logf(ev);
  for (int off = 32; off; off >>= 1) t += __shfl_xor(t, off);
  __shared__ float red[4];
  int w = d >> 6, lane = d & 63;
  if (lane == 0) red[w] = t;
  __syncthreads();
  if (d == 0) cl[hb] = red[0] + red[1] + red[2] + red[3];
}

// lm[g,lq,lp] = logmls(query, proto)
__global__ void k_lm(const float* __restrict__ P, const int* __restrict__ pos,
                     const float* __restrict__ pm, const float* __restrict__ pe,
                     float* __restrict__ lm) {
  int bb = blockIdx.x;             // g*64 + lq
  int g = bb >> 6, lq = bb & 63;
  int h = g >> 2;
  int d = threadIdx.x;
  int row = pos[lq * 8 + g];
  float mq = P[row * KK + d];
  float vq = expf(P[row * KK + DD + d]);
  __shared__ float part[4][64];
  int w = d >> 6, lane = d & 63;
  for (int lp = 0; lp < 64; ++lp) {
    int pb = (h * 64 + lp) * DD + d;
    float mp = pm[pb], ev = pe[pb];
    float vs = vq + ev;
    float diff = mq - mp;
    float t = __logf(vs) + diff * diff * __builtin_amdgcn_rcpf(vs);
    for (int off = 32; off; off >>= 1) t += __shfl_xor(t, off);
    if (lane == 0) part[w][lp] = t;
  }
  __syncthreads();
  if (d < 64) {
    float s = part[0][d] + part[1][d] + part[2][d] + part[3][d];
    lm[bb * 64 + d] = -0.5f * (256.0f * F_LOG2PI + s);
  }
}

// Hot kernel: block=(h, lq, dchunk of 16). wave w = query i, lane = lp.
// 2 passes of 8 independent threefry chains. Partial d-sums atomically
// accumulated into accbuf[((g*64+lq)*16+s)*64+lp].
__global__ __launch_bounds__(256) void k_tl(const float* __restrict__ P,
    const int* __restrict__ pos, const float4* __restrict__ pq,
    float* __restrict__ accbuf) {
  constexpr U2 S1 = tf2x32(0u, 42u, 0u, 0u);  // foldlike split of key(42)
  constexpr U2 S2 = tf2x32(0u, 42u, 0u, 1u);
  int bb = blockIdx.x;             // h*1024 + lq*16 + chunk
  int h = bb >> 10;
  int lq = (bb >> 4) & 63;
  int chunk = bb & 15;
  int t = threadIdx.x;

  __shared__ float2 q[4 * 256];    // [i][d] = {m, exp(h)}
#pragma unroll
  for (int i = 0; i < 4; ++i) {
    int row = pos[lq * 8 + h * 4 + i];
    float2 rec;
    rec.x = P[row * KK + t];
    rec.y = expf(P[row * KK + DD + t]);
    q[i * 256 + t] = rec;
  }
  __syncthreads();

  int w = t >> 6, lane = t & 63;   // w = query i, lane = lp
  unsigned k0 = h ? S2.x : S1.x;
  unsigned k1 = h ? S2.y : S1.y;
  // eps flat idx (per half) = i*PER_I + lq*262144 + s*16384 + lp*256 + d
  // k1 folded into the counter base (threefry x1 init = c1 + k1).
  unsigned ebk = (unsigned)w * PER_I + (unsigned)lq * 262144u +
                 (unsigned)lane * 256u + (unsigned)chunk * 16u + k1;
  const float2* qd = &q[w * 256];
  const float4* pp = pq + (h * 256 + chunk * 16) * 64 + lane;
  int g = h * 4 + w;
  float* dst = accbuf + ((g * 64 + lq) * 16) * 64 + lane;

#pragma unroll 1
  for (int pass = 0; pass < 2; ++pass) {
    float acc[8];
#pragma unroll
    for (int s = 0; s < 8; ++s) acc[s] = 0.0f;
    unsigned pbase = (unsigned)pass * 8u * 16384u;
#pragma unroll 1
    for (int dd = 0; dd < 16; ++dd) {
      float4 pr = pp[dd * 64];           // {mp, ev, ivp, -} coalesced, L2-hot
      float2 qv = qd[chunk * 16 + dd];   // broadcast ds_read_b64
      float vs  = qv.y + pr.y;
      float ivs = __builtin_amdgcn_rcpf(vs);
      float evs = pr.y * ivs;            // ev/vs
      float sivp = __builtin_amdgcn_sqrtf(pr.z);
      float A = (qv.x - pr.x) * evs * sivp;                // sign irrelevant (squared)
      float S = __builtin_amdgcn_sqrtf(qv.y * evs) * sivp * 1.41421356f; // sqrt2 folded
      unsigned ebkd = ebk + pbase + (unsigned)dd;
#pragma unroll
      for (int s = 0; s < 8; ++s) {
        unsigned bits = tf_fold(k0, k1, ebkd + (unsigned)s * 16384u);
        float eps = normal_pu(bits);
        float diff = fmaf(S, eps, A);
        acc[s] = fmaf(diff, diff, acc[s]);
      }
    }
#pragma unroll
    for (int s = 0; s < 8; ++s) atomicAdd(dst + (pass * 8 + s) * 64, acc[s]);
  }
}

// Merged: per (g,lq): 16 lse over lp (wave w does s=w*4..w*4+3), then
// MC = logsumexp_s(-lse) - log S, then scatter out.
__global__ void k_final(const float* __restrict__ lm, const float* __restrict__ accbuf,
                        const float* __restrict__ cl, const int* __restrict__ pos,
                        const int* __restrict__ lmap, float* __restrict__ out) {
  int bb = blockIdx.x;             // g*64 + lq
  int g = bb >> 6, lq = bb & 63;
  int h = g >> 2;
  int t = threadIdx.x, w = t >> 6, lane = t & 63;
  __shared__ float lsebuf[16];
  float clv = cl[h * 64 + lane];
#pragma unroll
  for (int j = 0; j < 4; ++j) {
    int s = w * 4 + j;
    float tlv = -0.5f * (clv + accbuf[(bb * 16 + s) * 64 + lane]);
    float mx = tlv;
    for (int off = 32; off; off >>= 1) mx = fmaxf(mx, __shfl_xor(mx, off));
    float se = expf(tlv - mx);
    for (int off = 32; off; off >>= 1) se += __shfl_xor(se, off);
    if (lane == 0) lsebuf[s] = mx + __logf(se);
  }
  __syncthreads();
  if (t < 64) {
    float a = (t < 16) ? -lsebuf[t] : -INFINITY;
    float mx = a;
    for (int off = 32; off; off >>= 1) mx = fmaxf(mx, __shfl_xor(mx, off));
    float e = (t < 16) ? expf(a - mx) : 0.0f;
    for (int off = 32; off; off >>= 1) e += __shfl_xor(e, off);
    float mc = mx + __logf(e) - 2.7725887f;   // - log(16)
    int row = pos[lq * 8 + g];
    out[row * 64 + lmap[t]] = lm[bb * 64 + t] + mc;
  }
}

// ---------------- launch ----------------
extern "C" void kernel_launch(void* const* d_in, const int* in_sizes, int n_in,
                              void* d_out, int out_size, void* d_ws, size_t ws_size,
                              hipStream_t stream) {
  (void)in_sizes; (void)n_in; (void)out_size; (void)ws_size;
  const float* P      = (const float*)d_in[0];   // (512, 512) f32
  const float* he     = (const float*)d_in[1];   // scalar
  const int*   labels = (const int*)d_in[2];     // (512,) int
  float* out = (float*)d_out;                    // (512, 64) f32

  float* ws = (float*)d_ws;
  float* accbuf = ws;                   // [8][64][16][64] = 524288 floats (2 MB)
  float4* pq = (float4*)(ws + 524288);  // [2][256][64] float4 = 131072 floats
  float* pm  = ws + 655360;             // [2][64][256]
  float* pe  = ws + 688128;             // [2][64][256]
  float* cl  = ws + 720896;             // [2][64]
  float* lmw = ws + 721024;             // [8][64][64]
  int*   pos = (int*)(ws + 753792);     // [512]
  int*   lmp = pos + 512;               // [64]

  hipMemsetAsync(accbuf, 0, 524288 * sizeof(float), stream);
  hipLaunchKernelGGL(k_sort,   dim3(1),    dim3(512), 0, stream, labels, pos, lmp);
  hipLaunchKernelGGL(k_protos, dim3(128),  dim3(256), 0, stream, P, he, pos, pm, pe, pq, cl);
  hipLaunchKernelGGL(k_lm,     dim3(512),  dim3(256), 0, stream, P, pos, pm, pe, lmw);
  hipLaunchKernelGGL(k_tl,     dim3(2048), dim3(256), 0, stream, P, pos, pq, accbuf);
  hipLaunchKernelGGL(k_final,  dim3(512),  dim3(256), 0, stream, lmw, accbuf, cl, pos, lmp, out);
}

// Round 7
// 423.082 us; speedup vs baseline: 1.1140x; 1.1140x over previous
//
#include <hip/hip_runtime.h>
#include <math.h>

// ---------------- sizes ----------------
#define DD 256
#define KK 512
#define LL 64
#define BB 8
#define SS 16
#define F_LOG2PI 1.83787706641f
#define PER_I 16777216u   // i-stride in per-half eps flat index (64*16*64*256)

// ---------------- threefry2x32 (JAX-compatible) ----------------
struct U2 { unsigned x, y; };

__host__ __device__ constexpr U2 tf2x32(unsigned k0, unsigned k1, unsigned c0, unsigned c1) {
  unsigned ks2 = k0 ^ k1 ^ 0x1BD11BDAu;
  unsigned x0 = c0 + k0;
  unsigned x1 = c1 + k1;
#define TFR(r) { x0 += x1; x1 = (x1 << (r)) | (x1 >> (32 - (r))); x1 ^= x0; }
  TFR(13) TFR(15) TFR(26) TFR(6)   x0 += k1;  x1 += ks2 + 1u;
  TFR(17) TFR(29) TFR(16) TFR(24)  x0 += ks2; x1 += k0 + 2u;
  TFR(13) TFR(15) TFR(26) TFR(6)   x0 += k0;  x1 += k1 + 3u;
  TFR(17) TFR(29) TFR(16) TFR(24)  x0 += k1;  x1 += ks2 + 4u;
  TFR(13) TFR(15) TFR(26) TFR(6)   x0 += ks2; x1 += k0 + 5u;
#undef TFR
  return U2{x0, x1};
}

// Single-instruction rotate-left via v_alignbit_b32.
__device__ inline unsigned rotl(unsigned x, unsigned r) {
  return __builtin_amdgcn_alignbit(x, x, 32u - r);
}

// Threefry with c0=0 and k1 pre-folded into the counter (x1 = c1 + k1).
// Returns x0 ^ x1 (the JAX partitionable 32-bit draw).
__device__ inline unsigned tf_fold(unsigned k0, unsigned k1, unsigned x1) {
  unsigned ks2 = k0 ^ k1 ^ 0x1BD11BDAu;
  unsigned x0 = k0;
#define TFR(r) { x0 += x1; x1 = rotl(x1, r); x1 ^= x0; }
  TFR(13u) TFR(15u) TFR(26u) TFR(6u)   x0 += k1;  x1 += ks2 + 1u;
  TFR(17u) TFR(29u) TFR(16u) TFR(24u)  x0 += ks2; x1 += k0 + 2u;
  TFR(13u) TFR(15u) TFR(26u) TFR(6u)   x0 += k0;  x1 += k1 + 3u;
  TFR(17u) TFR(29u) TFR(16u) TFR(24u)  x0 += k1;  x1 += ks2 + 4u;
  TFR(13u) TFR(15u) TFR(26u) TFR(6u)   x0 += ks2; x1 += k0 + 5u;
#undef TFR
  return x0 ^ x1;
}

// bits -> p*u (eps = sqrt2*p*u; sqrt2 folded into caller's scale).
// Fully branchless: BOTH polynomials evaluated straight-line (coeffs hoisted
// to SGPRs by the compiler), ONE final cndmask. Bit-identical arithmetic to
// the verified R4 version; no branches -> full cross-draw interleave.
__device__ inline float normal_pu(unsigned b) {
  float two_fp = __uint_as_float((b >> 9) | 0x40000000u);     // 2*(1+frac) in [2,4)
  float u = fmaxf(-0.99999994f, two_fp - 3.0f);               // == 2f-1 exactly
  float w = -__logf(fmaf(-u, u, 1.0f));                       // -log(1-u*u)
  // fast path poly (w < 5)
  float wwf = w - 2.5f;
  float pf =            2.81022636e-08f;
  pf = fmaf(pf, wwf,    3.43273939e-07f);
  pf = fmaf(pf, wwf,   -3.5233877e-06f);
  pf = fmaf(pf, wwf,   -4.39150654e-06f);
  pf = fmaf(pf, wwf,    0.00021858087f);
  pf = fmaf(pf, wwf,   -0.00125372503f);
  pf = fmaf(pf, wwf,   -0.00417768164f);
  pf = fmaf(pf, wwf,    0.246640727f);
  pf = fmaf(pf, wwf,    1.50140941f);
  // rare path poly (w >= 5)
  float wwr = __builtin_amdgcn_sqrtf(w) - 3.0f;
  float pr =           -0.000200214257f;
  pr = fmaf(pr, wwr,    0.000100950558f);
  pr = fmaf(pr, wwr,    0.00134934322f);
  pr = fmaf(pr, wwr,   -0.00367342844f);
  pr = fmaf(pr, wwr,    0.00573950773f);
  pr = fmaf(pr, wwr,   -0.0076224613f);
  pr = fmaf(pr, wwr,    0.00943887047f);
  pr = fmaf(pr, wwr,    1.00167406f);
  pr = fmaf(pr, wwr,    2.83297682f);
  float p = (w < 5.0f) ? pf : pr;
  return p * u;
}

// ---------------- kernels ----------------

// Stable counting-sort of balanced labels (robust to int64 labels).
__global__ void k_sort(const int* __restrict__ labels, int* __restrict__ pos,
                       int* __restrict__ lmap) {
  __shared__ int lab[512];
  __shared__ int cnt[64];
  __shared__ int mode;
  int t = threadIdx.x;
  int v = labels[t];
  if (t < 64) cnt[t] = 0;
  if (t == 0) mode = 0;
  __syncthreads();
  atomicAdd(&cnt[v & 63], 1);
  __syncthreads();
  if (t < 64 && cnt[t] != 8) mode = 1;
  __syncthreads();
  if (mode) v = labels[2 * t];           // int64 little-endian low words
  lab[t] = v & 63;
  __syncthreads();
  int c = lab[t];
  int o = 0;
  for (int j = 0; j < t; ++j) o += (lab[j] == c);
  pos[c * 8 + o] = t;
  if (t < 64) lmap[t] = t;
}

// Prototype fusion per (half, class l).
__global__ void k_protos(const float* __restrict__ P, const float* __restrict__ he_p,
                         const int* __restrict__ pos, float* __restrict__ pm,
                         float* __restrict__ pe, float4* __restrict__ pq,
                         float* __restrict__ cl) {
  int hb = blockIdx.x;             // h*64 + l
  int h = hb >> 6, l = hb & 63;
  int d = threadIdx.x;
  float eps_var = expf(he_p[0]);
  int soff = h ? 0 : 4;            // support rows for this half
  float sinv = 0.f, sminv = 0.f;
#pragma unroll
  for (int j = 0; j < 4; ++j) {
    int row = pos[l * 8 + soff + j];
    float m = P[row * KK + d];
    float hh = P[row * KK + DD + d];
    float vv = eps_var + expf(hh);
    float iv = 1.0f / vv;
    sinv += iv; sminv += m * iv;
  }
  float nv = 1.0f / sinv;
  float nm = nv * sminv;
  float ev = eps_var + nv;         // exp(h_proto)
  pm[hb * DD + d] = nm;
  pe[hb * DD + d] = ev;
  float4 rec; rec.x = nm; rec.y = ev; rec.z = 1.0f / ev; rec.w = 0.0f;
  pq[(h * 256 + d) * 64 + l] = rec;
  float t = F_LOG2PI + __logf(ev);
  for (int off = 32; off; off >>= 1) t += __shfl_xor(t, off);
  __shared__ float red[4];
  int w = d >> 6, lane = d & 63;
  if (lane == 0) red[w] = t;
  __syncthreads();
  if (d == 0) cl[hb] = red[0] + red[1] + red[2] + red[3];
}

// lm[g,lq,lp] = logmls(query, proto)
__global__ void k_lm(const float* __restrict__ P, const int* __restrict__ pos,
                     const float* __restrict__ pm, const float* __restrict__ pe,
                     float* __restrict__ lm) {
  int bb = blockIdx.x;             // g*64 + lq
  int g = bb >> 6, lq = bb & 63;
  int h = g >> 2;
  int d = threadIdx.x;
  int row = pos[lq * 8 + g];
  float mq = P[row * KK + d];
  float vq = expf(P[row * KK + DD + d]);
  __shared__ float part[4][64];
  int w = d >> 6, lane = d & 63;
  for (int lp = 0; lp < 64; ++lp) {
    int pb = (h * 64 + lp) * DD + d;
    float mp = pm[pb], ev = pe[pb];
    float vs = vq + ev;
    float diff = mq - mp;
    float t = __logf(vs) + diff * diff * __builtin_amdgcn_rcpf(vs);
    for (int off = 32; off; off >>= 1) t += __shfl_xor(t, off);
    if (lane == 0) part[w][lp] = t;
  }
  __syncthreads();
  if (d < 64) {
    float s = part[0][d] + part[1][d] + part[2][d] + part[3][d];
    lm[bb * 64 + d] = -0.5f * (256.0f * F_LOG2PI + s);
  }
}

// Hot kernel: block=(h, lq, dchunk of 16). wave w = query i, lane = lp.
// Single pass, 16 independent branchless threefry chains (R4 structure).
// Partial d-sums atomically accumulated into accbuf[((g*64+lq)*16+s)*64+lp].
__global__ __launch_bounds__(256) void k_tl(const float* __restrict__ P,
    const int* __restrict__ pos, const float4* __restrict__ pq,
    float* __restrict__ accbuf) {
  constexpr U2 S1 = tf2x32(0u, 42u, 0u, 0u);  // foldlike split of key(42)
  constexpr U2 S2 = tf2x32(0u, 42u, 0u, 1u);
  int bb = blockIdx.x;             // h*1024 + lq*16 + chunk
  int h = bb >> 10;
  int lq = (bb >> 4) & 63;
  int chunk = bb & 15;
  int t = threadIdx.x;

  __shared__ float2 q[4 * 256];    // [i][d] = {m, exp(h)}
#pragma unroll
  for (int i = 0; i < 4; ++i) {
    int row = pos[lq * 8 + h * 4 + i];
    float2 rec;
    rec.x = P[row * KK + t];
    rec.y = expf(P[row * KK + DD + t]);
    q[i * 256 + t] = rec;
  }
  __syncthreads();

  int w = t >> 6, lane = t & 63;   // w = query i, lane = lp
  unsigned k0 = h ? S2.x : S1.x;
  unsigned k1 = h ? S2.y : S1.y;
  // eps flat idx (per half) = i*PER_I + lq*262144 + s*16384 + lp*256 + d
  // k1 folded into the counter base (threefry x1 init = c1 + k1).
  unsigned ebk = (unsigned)w * PER_I + (unsigned)lq * 262144u +
                 (unsigned)lane * 256u + (unsigned)chunk * 16u + k1;
  const float2* qd = &q[w * 256];
  const float4* pp = pq + (h * 256 + chunk * 16) * 64 + lane;
  int g = h * 4 + w;
  float* dst = accbuf + ((g * 64 + lq) * 16) * 64 + lane;

  float acc[16];
#pragma unroll
  for (int s = 0; s < 16; ++s) acc[s] = 0.0f;

#pragma unroll 1
  for (int dd = 0; dd < 16; ++dd) {
    float4 pr = pp[dd * 64];           // {mp, ev, ivp, -} coalesced, L2-hot
    float2 qv = qd[chunk * 16 + dd];   // broadcast ds_read_b64
    float vs  = qv.y + pr.y;
    float ivs = __builtin_amdgcn_rcpf(vs);
    float evs = pr.y * ivs;            // ev/vs
    float sivp = __builtin_amdgcn_sqrtf(pr.z);
    float A = (qv.x - pr.x) * evs * sivp;                // sign irrelevant (squared)
    float S = __builtin_amdgcn_sqrtf(qv.y * evs) * sivp * 1.41421356f; // sqrt2 folded
    unsigned ebkd = ebk + (unsigned)dd;
#pragma unroll
    for (int s = 0; s < 16; ++s) {
      unsigned bits = tf_fold(k0, k1, ebkd + (unsigned)s * 16384u);
      float eps = normal_pu(bits);
      float diff = fmaf(S, eps, A);
      acc[s] = fmaf(diff, diff, acc[s]);
    }
  }
#pragma unroll
  for (int s = 0; s < 16; ++s) atomicAdd(dst + s * 64, acc[s]);
}

// Merged: per (g,lq): 16 lse over lp (wave w does s=w*4..w*4+3), then
// MC = logsumexp_s(-lse) - log S, then scatter out.
__global__ void k_final(const float* __restrict__ lm, const float* __restrict__ accbuf,
                        const float* __restrict__ cl, const int* __restrict__ pos,
                        const int* __restrict__ lmap, float* __restrict__ out) {
  int bb = blockIdx.x;             // g*64 + lq
  int g = bb >> 6, lq = bb & 63;
  int h = g >> 2;
  int t = threadIdx.x, w = t >> 6, lane = t & 63;
  __shared__ float lsebuf[16];
  float clv = cl[h * 64 + lane];
#pragma unroll
  for (int j = 0; j < 4; ++j) {
    int s = w * 4 + j;
    float tlv = -0.5f * (clv + accbuf[(bb * 16 + s) * 64 + lane]);
    float mx = tlv;
    for (int off = 32; off; off >>= 1) mx = fmaxf(mx, __shfl_xor(mx, off));
    float se = expf(tlv - mx);
    for (int off = 32; off; off >>= 1) se += __shfl_xor(se, off);
    if (lane == 0) lsebuf[s] = mx + __logf(se);
  }
  __syncthreads();
  if (t < 64) {
    float a = (t < 16) ? -lsebuf[t] : -INFINITY;
    float mx = a;
    for (int off = 32; off; off >>= 1) mx = fmaxf(mx, __shfl_xor(mx, off));
    float e = (t < 16) ? expf(a - mx) : 0.0f;
    for (int off = 32; off; off >>= 1) e += __shfl_xor(e, off);
    float mc = mx + __logf(e) - 2.7725887f;   // - log(16)
    int row = pos[lq * 8 + g];
    out[row * 64 + lmap[t]] = lm[bb * 64 + t] + mc;
  }
}

// ---------------- launch ----------------
extern "C" void kernel_launch(void* const* d_in, const int* in_sizes, int n_in,
                              void* d_out, int out_size, void* d_ws, size_t ws_size,
                              hipStream_t stream) {
  (void)in_sizes; (void)n_in; (void)out_size; (void)ws_size;
  const float* P      = (const float*)d_in[0];   // (512, 512) f32
  const float* he     = (const float*)d_in[1];   // scalar
  const int*   labels = (const int*)d_in[2];     // (512,) int
  float* out = (float*)d_out;                    // (512, 64) f32

  float* ws = (float*)d_ws;
  float* accbuf = ws;                   // [8][64][16][64] = 524288 floats (2 MB)
  float4* pq = (float4*)(ws + 524288);  // [2][256][64] float4 = 131072 floats
  float* pm  = ws + 655360;             // [2][64][256]
  float* pe  = ws + 688128;             // [2][64][256]
  float* cl  = ws + 720896;             // [2][64]
  float* lmw = ws + 721024;             // [8][64][64]
  int*   pos = (int*)(ws + 753792);     // [512]
  int*   lmp = pos + 512;               // [64]

  hipMemsetAsync(accbuf, 0, 524288 * sizeof(float), stream);
  hipLaunchKernelGGL(k_sort,   dim3(1),    dim3(512), 0, stream, labels, pos, lmp);
  hipLaunchKernelGGL(k_protos, dim3(128),  dim3(256), 0, stream, P, he, pos, pm, pe, pq, cl);
  hipLaunchKernelGGL(k_lm,     dim3(512),  dim3(256), 0, stream, P, pos, pm, pe, lmw);
  hipLaunchKernelGGL(k_tl,     dim3(2048), dim3(256), 0, stream, P, pos, pq, accbuf);
  hipLaunchKernelGGL(k_final,  dim3(512),  dim3(256), 0, stream, lmw, accbuf, cl, pos, lmp, out);
}

// Round 8
// 416.159 us; speedup vs baseline: 1.1325x; 1.0166x over previous
//
#include <hip/hip_runtime.h>
#include <math.h>

// ---------------- sizes ----------------
#define DD 256
#define KK 512
#define LL 64
#define BB 8
#define SS 16
#define F_LOG2PI 1.83787706641f
#define PER_I 16777216u   // i-stride in per-half eps flat index (64*16*64*256)

typedef float v2f __attribute__((ext_vector_type(2)));

// ---------------- threefry2x32 (JAX-compatible) ----------------
struct U2 { unsigned x, y; };

__host__ __device__ constexpr U2 tf2x32(unsigned k0, unsigned k1, unsigned c0, unsigned c1) {
  unsigned ks2 = k0 ^ k1 ^ 0x1BD11BDAu;
  unsigned x0 = c0 + k0;
  unsigned x1 = c1 + k1;
#define TFR(r) { x0 += x1; x1 = (x1 << (r)) | (x1 >> (32 - (r))); x1 ^= x0; }
  TFR(13) TFR(15) TFR(26) TFR(6)   x0 += k1;  x1 += ks2 + 1u;
  TFR(17) TFR(29) TFR(16) TFR(24)  x0 += ks2; x1 += k0 + 2u;
  TFR(13) TFR(15) TFR(26) TFR(6)   x0 += k0;  x1 += k1 + 3u;
  TFR(17) TFR(29) TFR(16) TFR(24)  x0 += k1;  x1 += ks2 + 4u;
  TFR(13) TFR(15) TFR(26) TFR(6)   x0 += ks2; x1 += k0 + 5u;
#undef TFR
  return U2{x0, x1};
}

// Single-instruction rotate-left via v_alignbit_b32.
__device__ inline unsigned rotl(unsigned x, unsigned r) {
  return __builtin_amdgcn_alignbit(x, x, 32u - r);
}

// Threefry with c0=0 and k1 pre-folded into the counter (x1 = c1 + k1).
// Returns x0 ^ x1 (the JAX partitionable 32-bit draw).
__device__ inline unsigned tf_fold(unsigned k0, unsigned k1, unsigned x1) {
  unsigned ks2 = k0 ^ k1 ^ 0x1BD11BDAu;
  unsigned x0 = k0;
#define TFR(r) { x0 += x1; x1 = rotl(x1, r); x1 ^= x0; }
  TFR(13u) TFR(15u) TFR(26u) TFR(6u)   x0 += k1;  x1 += ks2 + 1u;
  TFR(17u) TFR(29u) TFR(16u) TFR(24u)  x0 += ks2; x1 += k0 + 2u;
  TFR(13u) TFR(15u) TFR(26u) TFR(6u)   x0 += k0;  x1 += k1 + 3u;
  TFR(17u) TFR(29u) TFR(16u) TFR(24u)  x0 += k1;  x1 += ks2 + 4u;
  TFR(13u) TFR(15u) TFR(26u) TFR(6u)   x0 += ks2; x1 += k0 + 5u;
#undef TFR
  return x0 ^ x1;
}

// Packed fma helper: <2 x float> fma -> v_pk_fma_f32 on gfx90a+.
__device__ inline v2f pkfma(v2f a, v2f b, v2f c) {
#if __has_builtin(__builtin_elementwise_fma)
  return __builtin_elementwise_fma(a, b, c);
#else
  v2f r; r.x = fmaf(a.x, b.x, c.x); r.y = fmaf(a.y, b.y, c.y); return r;
#endif
}

// bits -> p*u (eps = sqrt2*p*u; sqrt2 folded into caller's scale).
// Branchless; both erfinv polynomials evaluated as ONE packed chain
// (v_pk_fma_f32), one final cndmask. Per-half arithmetic bit-identical
// to the verified scalar version.
__device__ inline float normal_pu(unsigned b) {
  float two_fp = __uint_as_float((b >> 9) | 0x40000000u);     // 2*(1+frac) in [2,4)
  float u = fmaxf(-0.99999994f, two_fp - 3.0f);               // == 2f-1 exactly
  float w = -__logf(fmaf(-u, u, 1.0f));                       // -log(1-u*u)
  v2f ww; ww.x = w - 2.5f; ww.y = __builtin_amdgcn_sqrtf(w) - 3.0f;
  v2f p2; p2.x = 2.81022636e-08f; p2.y = -0.000200214257f;
  p2 = pkfma(p2, ww, (v2f){ 3.43273939e-07f,  0.000100950558f});
  p2 = pkfma(p2, ww, (v2f){-3.5233877e-06f,   0.00134934322f});
  p2 = pkfma(p2, ww, (v2f){-4.39150654e-06f, -0.00367342844f});
  p2 = pkfma(p2, ww, (v2f){ 0.00021858087f,   0.00573950773f});
  p2 = pkfma(p2, ww, (v2f){-0.00125372503f,  -0.0076224613f});
  p2 = pkfma(p2, ww, (v2f){-0.00417768164f,   0.00943887047f});
  p2 = pkfma(p2, ww, (v2f){ 0.246640727f,     1.00167406f});
  p2 = pkfma(p2, ww, (v2f){ 1.50140941f,      2.83297682f});
  float p = (w < 5.0f) ? p2.x : p2.y;
  return p * u;
}

// ---------------- kernels ----------------

// Stable counting-sort of balanced labels (robust to int64 labels).
__global__ void k_sort(const int* __restrict__ labels, int* __restrict__ pos,
                       int* __restrict__ lmap) {
  __shared__ int lab[512];
  __shared__ int cnt[64];
  __shared__ int mode;
  int t = threadIdx.x;
  int v = labels[t];
  if (t < 64) cnt[t] = 0;
  if (t == 0) mode = 0;
  __syncthreads();
  atomicAdd(&cnt[v & 63], 1);
  __syncthreads();
  if (t < 64 && cnt[t] != 8) mode = 1;
  __syncthreads();
  if (mode) v = labels[2 * t];           // int64 little-endian low words
  lab[t] = v & 63;
  __syncthreads();
  int c = lab[t];
  int o = 0;
  for (int j = 0; j < t; ++j) o += (lab[j] == c);
  pos[c * 8 + o] = t;
  if (t < 64) lmap[t] = t;
}

// Prototype fusion per (half, class l). Emits protoQ float4[h][d][l] =
// {mp, ev, 1/ev, 0} (lp-coalesced) and cl[h][l] = sum_d(LOG2PI + log ev).
__global__ void k_protos(const float* __restrict__ P, const float* __restrict__ he_p,
                         const int* __restrict__ pos, float4* __restrict__ pq,
                         float* __restrict__ cl) {
  int hb = blockIdx.x;             // h*64 + l
  int h = hb >> 6, l = hb & 63;
  int d = threadIdx.x;
  float eps_var = expf(he_p[0]);
  int soff = h ? 0 : 4;            // support rows for this half
  float sinv = 0.f, sminv = 0.f;
#pragma unroll
  for (int j = 0; j < 4; ++j) {
    int row = pos[l * 8 + soff + j];
    float m = P[row * KK + d];
    float hh = P[row * KK + DD + d];
    float vv = eps_var + expf(hh);
    float iv = 1.0f / vv;
    sinv += iv; sminv += m * iv;
  }
  float nv = 1.0f / sinv;
  float nm = nv * sminv;
  float ev = eps_var + nv;         // exp(h_proto)
  float4 rec; rec.x = nm; rec.y = ev; rec.z = 1.0f / ev; rec.w = 0.0f;
  pq[(h * 256 + d) * 64 + l] = rec;
  float t = F_LOG2PI + __logf(ev);
  for (int off = 32; off; off >>= 1) t += __shfl_xor(t, off);
  __shared__ float red[4];
  int w = d >> 6, lane = d & 63;
  if (lane == 0) red[w] = t;
  __syncthreads();
  if (d == 0) cl[hb] = red[0] + red[1] + red[2] + red[3];
}

// lm[g,lq,lp] = logmls(query, proto) — serial-accumulator style:
// 1 wave per (g,lq), lane = lp, loop d with per-lane accumulation.
__global__ void k_lm(const float* __restrict__ P, const int* __restrict__ pos,
                     const float4* __restrict__ pq, float* __restrict__ lm) {
  int bb = blockIdx.x;             // g*64 + lq
  int g = bb >> 6, lq = bb & 63;
  int h = g >> 2;
  int lane = threadIdx.x;          // 64 threads: lp
  __shared__ float2 q[256];        // query row: {m, exp(h)} per d
  int row = pos[lq * 8 + g];
#pragma unroll
  for (int j = 0; j < 4; ++j) {
    int d = j * 64 + lane;
    float2 rec;
    rec.x = P[row * KK + d];
    rec.y = expf(P[row * KK + DD + d]);
    q[d] = rec;
  }
  __syncthreads();
  const float4* pp = pq + h * 256 * 64 + lane;
  float t = 0.0f;
#pragma unroll 4
  for (int d = 0; d < 256; ++d) {
    float4 pr = pp[d * 64];        // {mp, ev, -, -} coalesced, L2-hot
    float2 qv = q[d];              // broadcast
    float vs = qv.y + pr.y;
    float diff = qv.x - pr.x;
    t += __logf(vs) + diff * diff * __builtin_amdgcn_rcpf(vs);
  }
  lm[bb * 64 + lane] = -0.5f * (256.0f * F_LOG2PI + t);
}

// Hot kernel: block=(h, lq, dchunk of 16). wave w = query i, lane = lp.
// Single pass, 16 independent branchless threefry chains. Partial d-sums
// atomically accumulated into accbuf[((g*64+lq)*16+s)*64+lp].
__global__ __launch_bounds__(256) void k_tl(const float* __restrict__ P,
    const int* __restrict__ pos, const float4* __restrict__ pq,
    float* __restrict__ accbuf) {
  constexpr U2 S1 = tf2x32(0u, 42u, 0u, 0u);  // foldlike split of key(42)
  constexpr U2 S2 = tf2x32(0u, 42u, 0u, 1u);
  int bb = blockIdx.x;             // h*1024 + lq*16 + chunk
  int h = bb >> 10;
  int lq = (bb >> 4) & 63;
  int chunk = bb & 15;
  int t = threadIdx.x;

  __shared__ float2 q[4 * 256];    // [i][d] = {m, exp(h)}
#pragma unroll
  for (int i = 0; i < 4; ++i) {
    int row = pos[lq * 8 + h * 4 + i];
    float2 rec;
    rec.x = P[row * KK + t];
    rec.y = expf(P[row * KK + DD + t]);
    q[i * 256 + t] = rec;
  }
  __syncthreads();

  int w = t >> 6, lane = t & 63;   // w = query i, lane = lp
  unsigned k0 = h ? S2.x : S1.x;
  unsigned k1 = h ? S2.y : S1.y;
  // eps flat idx (per half) = i*PER_I + lq*262144 + s*16384 + lp*256 + d
  // k1 folded into the counter base (threefry x1 init = c1 + k1).
  unsigned ebk = (unsigned)w * PER_I + (unsigned)lq * 262144u +
                 (unsigned)lane * 256u + (unsigned)chunk * 16u + k1;
  const float2* qd = &q[w * 256];
  const float4* pp = pq + (h * 256 + chunk * 16) * 64 + lane;
  int g = h * 4 + w;
  float* dst = accbuf + ((g * 64 + lq) * 16) * 64 + lane;

  float acc[16];
#pragma unroll
  for (int s = 0; s < 16; ++s) acc[s] = 0.0f;

#pragma unroll 1
  for (int dd = 0; dd < 16; ++dd) {
    float4 pr = pp[dd * 64];           // {mp, ev, ivp, -} coalesced, L2-hot
    float2 qv = qd[chunk * 16 + dd];   // broadcast ds_read_b64
    float vs  = qv.y + pr.y;
    float ivs = __builtin_amdgcn_rcpf(vs);
    float evs = pr.y * ivs;            // ev/vs
    float sivp = __builtin_amdgcn_sqrtf(pr.z);
    float A = (qv.x - pr.x) * evs * sivp;                // sign irrelevant (squared)
    float S = __builtin_amdgcn_sqrtf(qv.y * evs) * sivp * 1.41421356f; // sqrt2 folded
    unsigned ebkd = ebk + (unsigned)dd;
#pragma unroll
    for (int s = 0; s < 16; ++s) {
      unsigned bits = tf_fold(k0, k1, ebkd + (unsigned)s * 16384u);
      float eps = normal_pu(bits);
      float diff = fmaf(S, eps, A);
      acc[s] = fmaf(diff, diff, acc[s]);
    }
  }
#pragma unroll
  for (int s = 0; s < 16; ++s) atomicAdd(dst + s * 64, acc[s]);
}

// Merged: per (g,lq): 16 lse over lp (wave w does s=w*4..w*4+3), then
// MC = logsumexp_s(-lse) - log S, then scatter out.
__global__ void k_final(const float* __restrict__ lm, const float* __restrict__ accbuf,
                        const float* __restrict__ cl, const int* __restrict__ pos,
                        const int* __restrict__ lmap, float* __restrict__ out) {
  int bb = blockIdx.x;             // g*64 + lq
  int g = bb >> 6, lq = bb & 63;
  int h = g >> 2;
  int t = threadIdx.x, w = t >> 6, lane = t & 63;
  __shared__ float lsebuf[16];
  float clv = cl[h * 64 + lane];
#pragma unroll
  for (int j = 0; j < 4; ++j) {
    int s = w * 4 + j;
    float tlv = -0.5f * (clv + accbuf[(bb * 16 + s) * 64 + lane]);
    float mx = tlv;
    for (int off = 32; off; off >>= 1) mx = fmaxf(mx, __shfl_xor(mx, off));
    float se = expf(tlv - mx);
    for (int off = 32; off; off >>= 1) se += __shfl_xor(se, off);
    if (lane == 0) lsebuf[s] = mx + __logf(se);
  }
  __syncthreads();
  if (t < 64) {
    float a = (t < 16) ? -lsebuf[t] : -INFINITY;
    float mx = a;
    for (int off = 32; off; off >>= 1) mx = fmaxf(mx, __shfl_xor(mx, off));
    float e = (t < 16) ? expf(a - mx) : 0.0f;
    for (int off = 32; off; off >>= 1) e += __shfl_xor(e, off);
    float mc = mx + __logf(e) - 2.7725887f;   // - log(16)
    int row = pos[lq * 8 + g];
    out[row * 64 + lmap[t]] = lm[bb * 64 + t] + mc;
  }
}

// ---------------- launch ----------------
extern "C" void kernel_launch(void* const* d_in, const int* in_sizes, int n_in,
                              void* d_out, int out_size, void* d_ws, size_t ws_size,
                              hipStream_t stream) {
  (void)in_sizes; (void)n_in; (void)out_size; (void)ws_size;
  const float* P      = (const float*)d_in[0];   // (512, 512) f32
  const float* he     = (const float*)d_in[1];   // scalar
  const int*   labels = (const int*)d_in[2];     // (512,) int
  float* out = (float*)d_out;                    // (512, 64) f32

  float* ws = (float*)d_ws;
  float* accbuf = ws;                   // [8][64][16][64] = 524288 floats (2 MB)
  float4* pq = (float4*)(ws + 524288);  // [2][256][64] float4 = 131072 floats
  float* cl  = ws + 655360;             // [2][64]
  float* lmw = ws + 655488;             // [8][64][64]
  int*   pos = (int*)(ws + 688256);     // [512]
  int*   lmp = pos + 512;               // [64]

  hipMemsetAsync(accbuf, 0, 524288 * sizeof(float), stream);
  hipLaunchKernelGGL(k_sort,   dim3(1),    dim3(512), 0, stream, labels, pos, lmp);
  hipLaunchKernelGGL(k_protos, dim3(128),  dim3(256), 0, stream, P, he, pos, pq, cl);
  hipLaunchKernelGGL(k_lm,     dim3(512),  dim3(64),  0, stream, P, pos, pq, lmw);
  hipLaunchKernelGGL(k_tl,     dim3(2048), dim3(256), 0, stream, P, pos, pq, accbuf);
  hipLaunchKernelGGL(k_final,  dim3(512),  dim3(256), 0, stream, lmw, accbuf, cl, pos, lmp, out);
}